// Round 3
// baseline (2829.671 us; speedup 1.0000x reference)
//
#include <hip/hip_runtime.h>
#include <math.h>

#define NND 420
#define MAXE 5120
#define MAXS 65536

// output layout (float element offsets)
#define OFF_X    ((size_t)0)
#define OFF_RI   ((size_t)25600)
#define OFF_RO   ((size_t)(25600 + 335544320))
#define OFF_SUY  ((size_t)671114240)
#define OFF_SIDS ((size_t)671179776)
#define OFF_NIDX ((size_t)671310848)
#define OFF_EIDS ((size_t)671315968)

typedef float f4 __attribute__((ext_vector_type(4)));

static __device__ __forceinline__ float f32(double d) { return (float)d; }

__device__ float g_r[NND], g_phi[NND], g_z[NND], g_st[NND], g_trk[NND], g_io[NND];
__device__ short g_ei[MAXE], g_ej[MAXE];
__device__ int   g_estart[NND + 1];
__device__ float g_dxn[MAXE], g_dyn[MAXE], g_dzn[MAXE], g_iop[MAXE], g_ioc[MAXE];
__device__ int   g_keep[MAXE], g_istrue[MAXE], g_jn[MAXE];
__device__ int   g_cnt2[MAXE], g_off2[MAXE];
__device__ int   g_nedges, g_nkeep;

// ---------------- kFill: zero whole output, -2 default in super_ids region.
// Nontemporal float4 stores; BW-bound target ~6 TB/s.
__global__ __launch_bounds__(256) void kFill(f4* __restrict__ p, size_t n4) {
    const size_t LO = OFF_SIDS >> 2;                       // float4-aligned
    const size_t HI = (OFF_SIDS + 2 * (size_t)MAXS) >> 2;  // float4-aligned
    size_t i = (size_t)blockIdx.x * 256 + threadIdx.x;
    size_t stride = (size_t)gridDim.x * 256;
    const f4 z = {0.f, 0.f, 0.f, 0.f};
    const f4 m = {-2.f, -2.f, -2.f, -2.f};
    for (; i < n4; i += stride) {
        f4 v = (i >= LO && i < HI) ? m : z;
        __builtin_nontemporal_store(v, p + i);
    }
}

// ---------------- kA1: node features + edge offsets + ordered edge list (1 block)
__global__ __launch_bounds__(512) void kA1(const float* __restrict__ ev) {
    __shared__ float s_st[NND];
    __shared__ int   s_scan[NND];
    int t = threadIdx.x;
    float stv = 0.0f;
    if (t < NND) {
        float x = ev[t * 7 + 1], y = ev[t * 7 + 2];
        g_r[t]   = sqrtf(__fadd_rn(__fmul_rn(x, x), __fmul_rn(y, y)));
        g_phi[t] = atan2f(x, y);           // reference: arctan2(x, y)
        g_z[t]   = ev[t * 7 + 3];
        stv      = ev[t * 7 + 4];
        g_st[t]  = stv;  s_st[t] = stv;
        g_trk[t] = ev[t * 7 + 5];
        g_io[t]  = ev[t * 7 + 6];
    }
    __syncthreads();
    int cnt = 0;
    if (t < NND) {
        float target = stv + 1.0f;
        for (int j = 0; j < NND; ++j) cnt += (s_st[j] == target) ? 1 : 0;
        s_scan[t] = cnt;
    }
    __syncthreads();
    // inclusive Hillis-Steele scan over 420 counts
    for (int off = 1; off < NND; off <<= 1) {
        int v = 0;
        if (t < NND && t >= off) v = s_scan[t - off];
        __syncthreads();
        if (t < NND) s_scan[t] += v;
        __syncthreads();
    }
    if (t < NND) {
        int excl = s_scan[t] - cnt;
        g_estart[t] = excl > MAXE ? MAXE : excl;
        int k = excl;
        float target = stv + 1.0f;
        for (int j = 0; j < NND; ++j) {
            if (s_st[j] == target) {
                if (k < MAXE) { g_ei[k] = (short)t; g_ej[k] = (short)j; }
                ++k;
            }
        }
        if (t == NND - 1) {
            g_nedges = s_scan[t];
            g_estart[NND] = s_scan[t] > MAXE ? MAXE : s_scan[t];
        }
    }
}

// ---------------- kA2: per-edge features + small outputs (10 blocks x 512)
__global__ __launch_bounds__(512) void kA2(float* __restrict__ out) {
    __shared__ float s_r[NND], s_phi[NND], s_z[NND], s_st[NND], s_trk[NND], s_io[NND];
    int t = threadIdx.x;
    for (int n = t; n < NND; n += 512) {
        s_r[n] = g_r[n]; s_phi[n] = g_phi[n]; s_z[n] = g_z[n];
        s_st[n] = g_st[n]; s_trk[n] = g_trk[n]; s_io[n] = g_io[n];
    }
    __syncthreads();

    const float PI_F  = f32(3.141592653589793);
    const float TPI_F = f32(6.283185307179586);
    const float LO1 = -3.15f, SPAN1 = 3.15f + 3.15f;
    const float LO2 = -2386.0f, SPAN2 = 4772.0f;
    const float SPAN0 = 312.0f;

    int k = blockIdx.x * 512 + t;
    if (k >= MAXE) return;
    int ne = g_nedges; if (ne > MAXE) ne = MAXE;
    bool valid = (k < ne);
    int i = valid ? (int)g_ei[k] : 0;
    int j = valid ? (int)g_ej[k] : 0;

    float phip = s_phi[i], phic = s_phi[j];
    float zp = s_z[i], zc = s_z[j];
    float rp = s_r[i], rc = s_r[j];
    float iop = s_io[i], ioc = s_io[j];
    int istrue = (s_trk[i] == s_trk[j]) ? 1 : 0;

    float d = __fsub_rn(phic, phip);
    if (d >  PI_F) d = __fsub_rn(d, TPI_F);
    if (d < -PI_F) d = __fadd_rn(d, TPI_F);

    float dzv = __fsub_rn(zc, zp);
    float dxv = __fsub_rn(rc, rp);
    float dxn = __fdiv_rn(__fmul_rn(2.0f, dxv), SPAN0);
    float dyn = __fdiv_rn(__fmul_rn(2.0f, d),   SPAN1);
    float dzn = __fdiv_rn(__fmul_rn(2.0f, dzv), SPAN2);

    bool keep = valid && (dyn > -10.0f) && (dyn < 10.0f)
                      && (dzn > -10.0f) && (dzn < 10.0f);

    float ypn = __fsub_rn(__fdiv_rn(__fmul_rn(2.0f, __fsub_rn(phip, LO1)), SPAN1), 1.0f);
    float ycn = __fsub_rn(__fdiv_rn(__fmul_rn(2.0f, __fsub_rn(phic, LO1)), SPAN1), 1.0f);
    float zpn = __fsub_rn(__fdiv_rn(__fmul_rn(2.0f, __fsub_rn(zp, LO2)), SPAN2), 1.0f);
    float zcn = __fsub_rn(__fdiv_rn(__fmul_rn(2.0f, __fsub_rn(zc, LO2)), SPAN2), 1.0f);
    float ez  = __fdiv_rn(__fadd_rn(s_st[i], 1.0f), 35.0f);

    size_t oX = OFF_X + (size_t)k * 5;
    out[oX + 0] = keep ? ypn : 0.0f;
    out[oX + 1] = keep ? ycn : 0.0f;
    out[oX + 2] = keep ? zpn : 0.0f;
    out[oX + 3] = keep ? zcn : 0.0f;
    out[oX + 4] = keep ? ez  : 0.0f;

    out[OFF_NIDX + (size_t)k] = keep ? (float)k : -1.0f;
    size_t oE = OFF_EIDS + (size_t)k * 3;
    out[oE + 0] = keep ? iop : -1.0f;
    out[oE + 1] = keep ? ioc : -1.0f;
    out[oE + 2] = keep ? (float)k : -1.0f;

    g_dxn[k] = dxn; g_dyn[k] = dyn; g_dzn[k] = dzn;
    g_iop[k] = iop; g_ioc[k] = ioc;
    g_keep[k] = keep ? 1 : 0; g_istrue[k] = istrue; g_jn[k] = j;
}

// ---------------- kB: one WAVE per a-edge, lane-parallel over b. 1280 blocks.
__global__ __launch_bounds__(256) void kB() {
    int gtid = blockIdx.x * 256 + threadIdx.x;
    int a = gtid >> 6, lane = gtid & 63;
    int c = 0;
    if (g_keep[a]) {                       // wave-uniform
        int jn = g_jn[a];
        int b0 = g_estart[jn], b1 = g_estart[jn + 1];
        float ioca = g_ioc[a];
        float a0 = g_dxn[a], a1 = g_dyn[a], a2 = g_dzn[a];
        for (int b = b0 + lane; b < b1; b += 64) {
            if (g_keep[b] && (g_iop[b] == ioca)) {
                float d0 = __fsub_rn(a0, g_dxn[b]);
                float d1 = __fsub_rn(a1, g_dyn[b]);
                float d2 = __fsub_rn(a2, g_dzn[b]);
                float w = sqrtf(__fadd_rn(__fadd_rn(__fmul_rn(d0, d0),
                                                    __fmul_rn(d1, d1)),
                                          __fmul_rn(d2, d2)));
                if (w < 0.1f) ++c;
            }
        }
    }
    for (int off = 32; off; off >>= 1) c += __shfl_down(c, off, 64);
    if (lane == 0) g_cnt2[a] = c;
}

// ---------------- kC: exclusive scan over 5120 counts (1 block)
__global__ __launch_bounds__(1024) void kC() {
    __shared__ int part[1024];
    int t = threadIdx.x;
    int v[5]; int s = 0;
#pragma unroll
    for (int q = 0; q < 5; ++q) { v[q] = g_cnt2[t * 5 + q]; s += v[q]; }
    part[t] = s;
    __syncthreads();
    for (int off = 1; off < 1024; off <<= 1) {
        int x = (t >= off) ? part[t - off] : 0;
        __syncthreads();
        part[t] += x;
        __syncthreads();
    }
    int run = part[t] - s;
#pragma unroll
    for (int q = 0; q < 5; ++q) { g_off2[t * 5 + q] = run; run += v[q]; }
    if (t == 1023) g_nkeep = part[1023];
}

// ---------------- kD: one WAVE per a-edge; order-preserving emission via ballot prefix
__global__ __launch_bounds__(256) void kD(float* __restrict__ out) {
    int gtid = blockIdx.x * 256 + threadIdx.x;
    int a = gtid >> 6, lane = gtid & 63;
    if (!g_keep[a]) return;                // wave-uniform
    int jn = g_jn[a];
    int b0 = g_estart[jn], b1 = g_estart[jn + 1];
    float ioca = g_ioc[a];
    float a0 = g_dxn[a], a1 = g_dyn[a], a2 = g_dzn[a];
    int ia = g_istrue[a];
    int base = g_off2[a];
    for (int cs = b0; cs < b1; cs += 64) {
        int b = cs + lane;
        bool pred = false;
        if (b < b1 && g_keep[b] && (g_iop[b] == ioca)) {
            float d0 = __fsub_rn(a0, g_dxn[b]);
            float d1 = __fsub_rn(a1, g_dyn[b]);
            float d2 = __fsub_rn(a2, g_dzn[b]);
            float w = sqrtf(__fadd_rn(__fadd_rn(__fmul_rn(d0, d0),
                                                __fmul_rn(d1, d1)),
                                      __fmul_rn(d2, d2)));
            pred = (w < 0.1f);
        }
        unsigned long long mask = __ballot(pred);
        if (pred) {
            int pos = base + (int)__popcll(mask & ((1ull << lane) - 1ull));
            if (pos < MAXS) {
                out[OFF_SUY + (size_t)pos] = (ia && g_istrue[b]) ? 1.0f : 0.0f;
                size_t os = OFF_SIDS + (size_t)pos * 2;
                out[os + 0] = (float)b;    // su_iop = e_index[se]
                out[os + 1] = (float)a;    // su_ioc = e_index[fi]
                out[OFF_RI + (size_t)a * MAXS + (size_t)pos] = 1.0f;
                out[OFF_RO + (size_t)b * MAXS + (size_t)pos] = 1.0f;
            }
        }
        base += (int)__popcll(mask);
    }
}

extern "C" void kernel_launch(void* const* d_in, const int* in_sizes, int n_in,
                              void* d_out, int out_size, void* d_ws, size_t ws_size,
                              hipStream_t stream) {
    const float* ev = (const float*)d_in[0];
    float* out = (float*)d_out;

    size_t n4 = (size_t)out_size / 4;
    hipLaunchKernelGGL(kFill, dim3(4096), dim3(256), 0, stream, (f4*)out, n4);
    hipLaunchKernelGGL(kA1, dim3(1), dim3(512), 0, stream, ev);
    hipLaunchKernelGGL(kA2, dim3((MAXE + 511) / 512), dim3(512), 0, stream, out);
    hipLaunchKernelGGL(kB, dim3(MAXE * 64 / 256), dim3(256), 0, stream);
    hipLaunchKernelGGL(kC, dim3(1), dim3(1024), 0, stream);
    hipLaunchKernelGGL(kD, dim3(MAXE * 64 / 256), dim3(256), 0, stream, out);
}